// Round 2
// baseline (155.065 us; speedup 1.0000x reference)
//
#include <hip/hip_runtime.h>
#include <hip/hip_bf16.h>

#define BN 8192
#define DIM 512
#define NB  64            // BN / 128 block-rows
#define NTILES 2080       // NB*(NB+1)/2 upper-triangle tiles
#define EPSF 1e-8f

using v8i   = __attribute__((ext_vector_type(8))) int;
using v4i   = __attribute__((ext_vector_type(4))) int;
using f32x4 = __attribute__((ext_vector_type(4))) float;

// Native exp2 (single v_exp_f32); fallback keeps exact semantics.
#if __has_builtin(__builtin_amdgcn_exp2f)
#define EXP2F(x) __builtin_amdgcn_exp2f(x)
#else
#define EXP2F(x) __expf((x) * 0.69314718055994531f)
#endif

// One wave per row: L2-normalize, x4 pre-scale, fp8 e4m3; out[0] zeroed by
// block 0 (replaces a memset dispatch). emb reads are non-temporal so the
// dead fp32 data doesn't evict E from L2 before gemm reads it.
__global__ __launch_bounds__(256) void normalize_kernel(
        const float* __restrict__ emb, unsigned char* __restrict__ E,
        float* __restrict__ out) {
    if (blockIdx.x == 0 && threadIdx.x == 0) out[0] = 0.f;
    int lane = threadIdx.x & 63;
    int row  = blockIdx.x * 4 + (threadIdx.x >> 6);
    const f32x4* src = (const f32x4*)(emb + (size_t)row * DIM);
    f32x4 a = __builtin_nontemporal_load(&src[lane]);
    f32x4 b = __builtin_nontemporal_load(&src[lane + 64]);
    float ss = a[0]*a[0] + a[1]*a[1] + a[2]*a[2] + a[3]*a[3]
             + b[0]*b[0] + b[1]*b[1] + b[2]*b[2] + b[3]*b[3];
    #pragma unroll
    for (int m = 1; m < 64; m <<= 1) ss += __shfl_xor(ss, m, 64);
    float s4 = 4.0f / fmaxf(sqrtf(ss), 1e-12f);
    int pa = __builtin_amdgcn_cvt_pk_fp8_f32(a[0]*s4, a[1]*s4, 0, false);
    pa     = __builtin_amdgcn_cvt_pk_fp8_f32(a[2]*s4, a[3]*s4, pa, true);
    int pb = __builtin_amdgcn_cvt_pk_fp8_f32(b[0]*s4, b[1]*s4, 0, false);
    pb     = __builtin_amdgcn_cvt_pk_fp8_f32(b[2]*s4, b[3]*s4, pb, true);
    unsigned char* rowp = E + (size_t)row * DIM;
    ((unsigned*)rowp)[lane]         = (unsigned)pa;
    ((unsigned*)(rowp + 256))[lane] = (unsigned)pb;
}

// Upper-triangle 128x128 tiles, 1D grid (2080), triangular decode.
// fp8 MX MFMA 16x16x128. BOTH A and B stream global->VGPR (E is ~L2
// resident, 4 MB) with a register double-buffer and a 1-k-step prefetch
// distance: ZERO barriers in the main loop. The A-fragment layout equals
// the B-fragment layout (row = i_w+ti*16+lrow, bytes k*128+quad*32..+32),
// so no LDS transpose/staging is needed at all. Each wave is an
// independent stream: a slow L2/L3 load stalls only its own wave (no
// block-wide convoy at a barrier), hidden by MFMA + the co-resident wave.
// Only 2 barriers/block remain (label visibility, reduction buffers).
// Epilogue (proven in prior rounds): exp2-fused weights, neg = tot - pos,
// per-row partials in rowBuf, per-col in colBuf, diag tiles exclude the
// self pair and skip the col path.
__global__ __launch_bounds__(256) void gemm_epi_kernel(
        const unsigned char* __restrict__ E, const int* __restrict__ labels,
        float* __restrict__ P, float* __restrict__ N) {
    __shared__ __attribute__((aligned(16))) float2 rowBuf[2 * 128 * 17]; // 34816 B
    __shared__ __attribute__((aligned(16))) float2 colBuf[2 * 128 * 5];  // 10240 B
    __shared__ int labI[128];
    __shared__ int labJ[128];

    int t  = blockIdx.x;
    int bi = (int)(64.5f - sqrtf(64.5f * 64.5f - 2.0f * (float)t));
    while (64 * (bi + 1) - ((bi + 1) * bi) / 2 <= t) ++bi;
    while (64 * bi - (bi * (bi - 1)) / 2 > t) --bi;
    int bj = bi + (t - (64 * bi - (bi * (bi - 1)) / 2));
    const bool diag = (bi == bj);
    const int i0 = bi * 128;
    const int j0 = bj * 128;

    const int tid  = threadIdx.x;
    const int wave = tid >> 6;
    const int lane = tid & 63;
    const int quad = lane >> 4;
    const int lrow = lane & 15;
    const int i_w  = (wave >> 1) * 64;
    const int j_w  = (wave & 1) * 64;

    if (tid < 128)       labI[tid]       = labels[i0 + tid];
    else                 labJ[tid - 128] = labels[j0 + tid - 128];

    const int vR = wave & 1;
    const int vC = wave >> 1;

    f32x4 acc[4][4];
    #pragma unroll
    for (int a = 0; a < 4; ++a)
        #pragma unroll
        for (int b = 0; b < 4; ++b)
            acc[a][b] = (f32x4){0.f, 0.f, 0.f, 0.f};

    // Per-lane fragment base pointers; element [m] = byte offset 16*m.
    // Fragment for k-step k: v4i indices k*8 and k*8+1 (32 B contiguous).
    const v4i* ap[4];
    const v4i* bp[4];
    #pragma unroll
    for (int x = 0; x < 4; ++x) {
        ap[x] = (const v4i*)(E +
            (size_t)(i0 + i_w + x * 16 + lrow) * DIM + quad * 32);
        bp[x] = (const v4i*)(E +
            (size_t)(j0 + j_w + x * 16 + lrow) * DIM + quad * 32);
    }

    v8i af[2][4], bf[2][4];
    #pragma unroll
    for (int x = 0; x < 4; ++x) {          // prologue: k=0 fragments
        ((v4i*)&af[0][x])[0] = ap[x][0];
        ((v4i*)&af[0][x])[1] = ap[x][1];
        ((v4i*)&bf[0][x])[0] = bp[x][0];
        ((v4i*)&bf[0][x])[1] = bp[x][1];
    }

    #pragma unroll
    for (int k = 0; k < 4; ++k) {
        const int cur = k & 1, nxt = cur ^ 1;
        if (k < 3) {                       // issue k+1 loads before MFMAs
            #pragma unroll
            for (int x = 0; x < 4; ++x) {
                ((v4i*)&af[nxt][x])[0] = ap[x][(k + 1) * 8];
                ((v4i*)&af[nxt][x])[1] = ap[x][(k + 1) * 8 + 1];
                ((v4i*)&bf[nxt][x])[0] = bp[x][(k + 1) * 8];
                ((v4i*)&bf[nxt][x])[1] = bp[x][(k + 1) * 8 + 1];
            }
        }
        __builtin_amdgcn_s_setprio(1);
        #pragma unroll
        for (int ti = 0; ti < 4; ++ti)
            #pragma unroll
            for (int tj = 0; tj < 4; ++tj)
                acc[ti][tj] =
                    __builtin_amdgcn_mfma_scale_f32_16x16x128_f8f6f4(
                        af[cur][ti], bf[cur][tj], acc[ti][tj],
                        0, 0,                 // fp8 e4m3 / e4m3
                        0, 0x7F7F7F7F,        // A scale = 1.0
                        0, 0x7F7F7F7F);       // B scale = 1.0
        __builtin_amdgcn_s_setprio(0);
    }

    __syncthreads();      // labI/labJ writes visible to all waves

    // Epilogue. C/D: col = lane&15, row = quad*4 + reg. acc = 16*S.
    // w = exp(S-1) = exp2(acc * log2e/16 - log2e).
    const float K1 = 0.0901619783824569f;    // log2(e)/16
    const float K2 = -1.4426950408889634f;   // -log2(e)
    if (!diag) {
        float psC[4] = {0.f, 0.f, 0.f, 0.f};
        float tsC[4] = {0.f, 0.f, 0.f, 0.f};
        #pragma unroll
        for (int ti = 0; ti < 4; ++ti) {
            #pragma unroll
            for (int reg = 0; reg < 4; ++reg) {
                int irow = i_w + ti * 16 + quad * 4 + reg;
                int li   = labI[irow];
                float ps = 0.f, ts = 0.f;
                #pragma unroll
                for (int tj = 0; tj < 4; ++tj) {
                    int jcol = j_w + tj * 16 + lrow;
                    float w  = EXP2F(fmaf(acc[ti][tj][reg], K1, K2));
                    float wp = (li == labJ[jcol]) ? w : 0.f;
                    ps += wp;  ts += w;
                    psC[tj] += wp;  tsC[tj] += w;
                }
                rowBuf[(size_t)(vR * 128 + irow) * 17 + lrow] =
                    (float2){ps, ts - ps};
            }
        }
        #pragma unroll
        for (int tj = 0; tj < 4; ++tj) {
            int jcol = j_w + tj * 16 + lrow;
            colBuf[(size_t)(vC * 128 + jcol) * 5 + quad] =
                (float2){psC[tj], tsC[tj] - psC[tj]};
        }
    } else {
        // Diag tile: self pair (irow == jcol) excluded from pos exactly;
        // col sums unused (row path covers the full square).
        #pragma unroll
        for (int ti = 0; ti < 4; ++ti) {
            #pragma unroll
            for (int reg = 0; reg < 4; ++reg) {
                int irow = i_w + ti * 16 + quad * 4 + reg;
                int li   = labI[irow];
                float ps = 0.f, ts = 0.f, sf = 0.f;
                #pragma unroll
                for (int tj = 0; tj < 4; ++tj) {
                    int jcol = j_w + tj * 16 + lrow;
                    float w  = EXP2F(fmaf(acc[ti][tj][reg], K1, K2));
                    float wp = (li == labJ[jcol]) ? w : 0.f;
                    float wd = (irow == jcol) ? w : 0.f;
                    ps += wp;  ts += w;  sf += wd;
                }
                rowBuf[(size_t)(vR * 128 + irow) * 17 + lrow] =
                    (float2){ps - sf, ts - ps};
            }
        }
    }
    __syncthreads();

    if (tid < 128) {
        const float2* a = rowBuf + (size_t)tid * 17;
        const float2* b = rowBuf + (size_t)(128 + tid) * 17;
        float sp = 0.f, sn = 0.f;
        #pragma unroll
        for (int u = 0; u < 16; ++u) {
            sp += a[u].x + b[u].x;
            sn += a[u].y + b[u].y;
        }
        __builtin_nontemporal_store(sp, &P[(size_t)bj * BN + i0 + tid]);
        __builtin_nontemporal_store(sn, &N[(size_t)bj * BN + i0 + tid]);
    } else if (!diag) {
        int c2 = tid - 128;
        const float2* a = colBuf + (size_t)c2 * 5;
        const float2* b = colBuf + (size_t)(128 + c2) * 5;
        float sp = 0.f, sn = 0.f;
        #pragma unroll
        for (int u = 0; u < 4; ++u) {
            sp += a[u].x + b[u].x;
            sn += a[u].y + b[u].y;
        }
        __builtin_nontemporal_store(sp, &P[(size_t)bi * BN + j0 + c2]);
        __builtin_nontemporal_store(sn, &N[(size_t)bi * BN + j0 + c2]);
    }
}

// Fused tail: 64 blocks x 128 (2x the CU coverage of the old 32x256).
// Per-block LDS histogram, per-row partial reduce + loss, one atomicAdd
// of the pre-scaled block sum into out[0]. P/N read non-temporally.
__global__ __launch_bounds__(128) void reduce_finalize_kernel(
        const int* __restrict__ labels, const float* __restrict__ P,
        const float* __restrict__ N, float* __restrict__ out) {
    __shared__ int cnt[128];
    __shared__ float wsum[2];
    int tid = threadIdx.x;
    cnt[tid] = 0;
    __syncthreads();
    for (int i = tid; i < BN; i += 128) atomicAdd(&cnt[labels[i]], 1);
    __syncthreads();

    int i = blockIdx.x * 128 + tid;
    float p = 0.f, n = 0.f;
    #pragma unroll 8
    for (int c = 0; c < NB; ++c) {
        p += __builtin_nontemporal_load(&P[(size_t)c * BN + i]);
        n += __builtin_nontemporal_load(&N[(size_t)c * BN + i]);
    }
    int   cl = cnt[labels[i]];
    float pm = p / fmaxf((float)(cl - 1), 1.0f);
    float nm = n / fmaxf((float)(BN - cl), 1.0f);
    float v  = ((cl - 1 > 0) && (BN - cl > 0))
                   ? -logf(pm / (pm + nm + EPSF)) : 0.0f;
    v *= (1.0f / (float)BN);
    #pragma unroll
    for (int m = 1; m < 64; m <<= 1) v += __shfl_xor(v, m, 64);
    if ((tid & 63) == 0) wsum[tid >> 6] = v;
    __syncthreads();
    if (tid == 0)
        atomicAdd(out, wsum[0] + wsum[1]);
}

extern "C" void kernel_launch(void* const* d_in, const int* in_sizes, int n_in,
                              void* d_out, int out_size, void* d_ws, size_t ws_size,
                              hipStream_t stream) {
    const float* emb   = (const float*)d_in[0];
    const int* labels  = (const int*)d_in[1];
    float* out         = (float*)d_out;

    // ws layout: E (8 MB reserved; fp8 uses 4) | P (2 MB) | N (2 MB)
    unsigned char* E   = (unsigned char*)d_ws;
    float* P           = (float*)((char*)d_ws + (size_t)BN * DIM * 2);
    float* N           = P + (size_t)NB * BN;

    normalize_kernel<<<BN / 4, 256, 0, stream>>>(emb, E, out);
    gemm_epi_kernel<<<NTILES, 256, 0, stream>>>(E, labels, P, N);
    reduce_finalize_kernel<<<64, 128, 0, stream>>>(labels, P, N, out);
}

// Round 3
// 150.977 us; speedup vs baseline: 1.0271x; 1.0271x over previous
//
#include <hip/hip_runtime.h>
#include <hip/hip_bf16.h>

#define BN 8192
#define DIM 512
#define NB  64            // BN / 128 block-rows
#define NTILES 2080       // NB*(NB+1)/2 upper-triangle tiles
#define EPSF 1e-8f

using v8i   = __attribute__((ext_vector_type(8))) int;
using v4i   = __attribute__((ext_vector_type(4))) int;
using f32x4 = __attribute__((ext_vector_type(4))) float;
using f32x2 = __attribute__((ext_vector_type(2))) float;

// Native exp2 (single v_exp_f32); fallback keeps exact semantics.
#if __has_builtin(__builtin_amdgcn_exp2f)
#define EXP2F(x) __builtin_amdgcn_exp2f(x)
#else
#define EXP2F(x) __expf((x) * 0.69314718055994531f)
#endif

__device__ __forceinline__ f32x2 shfl_xor2(f32x2 v, int m) {
    f32x2 r;
    r[0] = __shfl_xor(v[0], m, 64);
    r[1] = __shfl_xor(v[1], m, 64);
    return r;
}

// Async global->LDS, 16 B per lane, dest = uniform base + lane*16.
__device__ __forceinline__ void async_copy16(const void* g, void* l) {
    __builtin_amdgcn_global_load_lds(
        (const __attribute__((address_space(1))) void*)g,
        (__attribute__((address_space(3))) void*)l,
        16, 0, 0);
}

// One wave per row: L2-normalize, x4 pre-scale, fp8 e4m3; out[0] zeroed by
// block 0 (replaces a memset dispatch).
__global__ __launch_bounds__(256) void normalize_kernel(
        const float* __restrict__ emb, unsigned char* __restrict__ E,
        float* __restrict__ out) {
    if (blockIdx.x == 0 && threadIdx.x == 0) out[0] = 0.f;
    int lane = threadIdx.x & 63;
    int row  = blockIdx.x * 4 + (threadIdx.x >> 6);
    const float4* src = (const float4*)(emb + (size_t)row * DIM);
    float4 a = src[lane];
    float4 b = src[lane + 64];
    float ss = a.x*a.x + a.y*a.y + a.z*a.z + a.w*a.w
             + b.x*b.x + b.y*b.y + b.z*b.z + b.w*b.w;
    #pragma unroll
    for (int m = 1; m < 64; m <<= 1) ss += __shfl_xor(ss, m, 64);
    float s4 = 4.0f / fmaxf(sqrtf(ss), 1e-12f);
    int pa = __builtin_amdgcn_cvt_pk_fp8_f32(a.x*s4, a.y*s4, 0, false);
    pa     = __builtin_amdgcn_cvt_pk_fp8_f32(a.z*s4, a.w*s4, pa, true);
    int pb = __builtin_amdgcn_cvt_pk_fp8_f32(b.x*s4, b.y*s4, 0, false);
    pb     = __builtin_amdgcn_cvt_pk_fp8_f32(b.z*s4, b.w*s4, pb, true);
    unsigned char* rowp = E + (size_t)row * DIM;
    ((unsigned*)rowp)[lane]         = (unsigned)pa;
    ((unsigned*)(rowp + 256))[lane] = (unsigned)pb;
}

// Upper-triangle 128x128 tiles, 1D grid (2080), triangular decode.
// fp8 MX MFMA 16x16x128. Main loop = round-1 proven structure: A staged in
// LDS as 4 chunks of BK=128 (16 KB) double-buffered with counted vmcnt(8)
// + raw s_barrier (stage(k+1) + B-prefetch(k+1) stay in flight across the
// barrier); B streams global->VGPR register-double-buffered.
// NEW: epilogue row/col reduction done with in-register shfl_xor butterfly
// (multi-value recursive halving) instead of a 34.8 KB LDS buffer; only
// rowSum/colSum[2][128] f32x2 (4 KB) remain. LDS 46 -> 37.9 KB => 4
// blocks/CU resident (was 3): +33% waves to fill barrier/latency stalls.
__global__ __launch_bounds__(256) void gemm_epi_kernel(
        const unsigned char* __restrict__ E, const int* __restrict__ labels,
        float* __restrict__ P, float* __restrict__ N) {
    __shared__ __attribute__((aligned(16))) unsigned char As[2 * 16384];
    __shared__ f32x2 rowSum[2][128];      // slot = wave&1 (j-half)
    __shared__ f32x2 colSum[2][128];      // slot = wave>>1 (i-half)
    __shared__ int labI[128];
    __shared__ int labJ[128];

    int t  = blockIdx.x;
    int bi = (int)(64.5f - sqrtf(64.5f * 64.5f - 2.0f * (float)t));
    while (64 * (bi + 1) - ((bi + 1) * bi) / 2 <= t) ++bi;
    while (64 * bi - (bi * (bi - 1)) / 2 > t) --bi;
    int bj = bi + (t - (64 * bi - (bi * (bi - 1)) / 2));
    const bool diag = (bi == bj);
    const int i0 = bi * 128;
    const int j0 = bj * 128;

    const int tid  = threadIdx.x;
    const int wave = tid >> 6;
    const int lane = tid & 63;
    const int quad = lane >> 4;
    const int lrow = lane & 15;
    const int i_w  = (wave >> 1) * 64;
    const int j_w  = (wave & 1) * 64;

    if (tid < 128)       labI[tid]       = labels[i0 + tid];
    else                 labJ[tid - 128] = labels[j0 + tid - 128];

    const int vR = wave & 1;
    const int vC = wave >> 1;

    f32x4 acc[4][4];
    #pragma unroll
    for (int a = 0; a < 4; ++a)
        #pragma unroll
        for (int b = 0; b < 4; ++b)
            acc[a][b] = (f32x4){0.f, 0.f, 0.f, 0.f};

    const v4i* bptr[4];
    #pragma unroll
    for (int tj = 0; tj < 4; ++tj)
        bptr[tj] = (const v4i*)(E +
            (size_t)(j0 + j_w + tj * 16 + lrow) * DIM + quad * 32);

    v8i bf[2][4];
    #pragma unroll
    for (int tj = 0; tj < 4; ++tj) {      // prefetch B for k=0
        ((v4i*)&bf[0][tj])[0] = bptr[tj][0];
        ((v4i*)&bf[0][tj])[1] = bptr[tj][1];
    }

    // Staging lane constants: each wave covers rows [wave*32, wave*32+32),
    // 4 calls x 8 rows; lane l -> row (l>>3), LDS chunk l&7 holds global
    // chunk (l&7)^(l>>3)  (row&7 == l>>3 since bases are multiples of 8).
    const int stRow = lane >> 3;
    const int stChk = (lane & 7) ^ stRow;
    const unsigned char* gA = E + (size_t)(i0 + wave * 32 + stRow) * DIM
                                + stChk * 16;
    const int sw = lrow & 7;

    // Prologue: stage chunk 0 into buf0, full drain, barrier.
    #pragma unroll
    for (int h = 0; h < 4; ++h)
        async_copy16(gA + (size_t)h * 8 * DIM,
                     As + (size_t)(wave * 32 + h * 8) * 128);
    asm volatile("s_waitcnt vmcnt(0)" ::: "memory");
    __builtin_amdgcn_s_barrier();

    #pragma unroll
    for (int k = 0; k < 4; ++k) {
        const int cur = k & 1;
        unsigned char* bufC = As + (size_t)cur * 16384;
        if (k < 3) {                      // issue stage(k+1) -> other buffer
            unsigned char* bufN = As + (size_t)(cur ^ 1) * 16384;
            #pragma unroll
            for (int h = 0; h < 4; ++h)
                async_copy16(gA + (size_t)h * 8 * DIM + (k + 1) * 128,
                             bufN + (size_t)(wave * 32 + h * 8) * 128);
        }
        v8i af[4];
        #pragma unroll
        for (int ti = 0; ti < 4; ++ti) {
            int r = i_w + ti * 16 + lrow;
            const v4i* rp = (const v4i*)(bufC + (size_t)r * 128);
            ((v4i*)&af[ti])[0] = rp[(quad * 2) ^ sw];
            ((v4i*)&af[ti])[1] = rp[(quad * 2 + 1) ^ sw];
        }
        if (k < 3) {                      // prefetch next k's B
            #pragma unroll
            for (int tj = 0; tj < 4; ++tj) {
                ((v4i*)&bf[cur ^ 1][tj])[0] = bptr[tj][(k + 1) * 8];
                ((v4i*)&bf[cur ^ 1][tj])[1] = bptr[tj][(k + 1) * 8 + 1];
            }
        }
        #pragma unroll
        for (int ti = 0; ti < 4; ++ti)
            #pragma unroll
            for (int tj = 0; tj < 4; ++tj)
                acc[ti][tj] =
                    __builtin_amdgcn_mfma_scale_f32_16x16x128_f8f6f4(
                        af[ti], bf[cur][tj], acc[ti][tj],
                        0, 0,                 // fp8 e4m3 / e4m3
                        0, 0x7F7F7F7F,        // A scale = 1.0
                        0, 0x7F7F7F7F);       // B scale = 1.0
        if (k < 3) {
            // Retire only the 4 stage(k+1) loads (oldest); leave the 8
            // B(k+1) prefetch loads in flight across the barrier.
            asm volatile("s_waitcnt vmcnt(8)" ::: "memory");
            __builtin_amdgcn_s_barrier();
        }
    }
    // labI/labJ were written before the prologue barrier -> visible.

    // Epilogue. C/D: col = lane&15, row = quad*4 + reg. acc = 16*S.
    // w = exp(S-1) = exp2(acc * log2e/16 - log2e).
    // Per-lane (pos, neg) pairs reduced with a shfl_xor butterfly:
    //  rows: 4 reg-values over 16 lanes (2 select-steps + 2 plain steps),
    //  cols: plain 2-step reduce over quads. Only 4 KB LDS remains.
    const float K1 = 0.0901619783824569f;    // log2(e)/16
    const float K2 = -1.4426950408889634f;   // -log2(e)
    const bool b0 = (lrow & 1) != 0;
    const bool b1 = (lrow & 2) != 0;

    f32x2 csum[4];
    #pragma unroll
    for (int tj = 0; tj < 4; ++tj) csum[tj] = (f32x2){0.f, 0.f};

    #pragma unroll
    for (int ti = 0; ti < 4; ++ti) {
        f32x2 pn[4];
        #pragma unroll
        for (int reg = 0; reg < 4; ++reg) {
            int irow = i_w + ti * 16 + quad * 4 + reg;
            int li   = labI[irow];
            float pos = 0.f, ts = 0.f, sf = 0.f;
            #pragma unroll
            for (int tj = 0; tj < 4; ++tj) {
                int jcol = j_w + tj * 16 + lrow;
                float w  = EXP2F(fmaf(acc[ti][tj][reg], K1, K2));
                float ws = (li == labJ[jcol]) ? w : 0.f;
                pos += ws;  ts += w;
                if (diag) sf += (irow == jcol) ? w : 0.f;
                csum[tj][0] += ws;
                csum[tj][1] += w;
            }
            // (pos excl self, neg) -- sf is 0 on off-diag tiles.
            pn[reg] = (f32x2){pos - sf, ts - pos};
        }
        // Butterfly: step A (mask 1) combines reg pairs {0,1},{2,3};
        // keep reg bit0 == b0.
        f32x2 s01 = b0 ? pn[0] : pn[1];
        f32x2 q0  = (b0 ? pn[1] : pn[0]) + shfl_xor2(s01, 1);  // reg = b0
        f32x2 s23 = b0 ? pn[2] : pn[3];
        f32x2 q1  = (b0 ? pn[3] : pn[2]) + shfl_xor2(s23, 1);  // reg = 2+b0
        // step B (mask 2): keep reg bit1 == b1.
        f32x2 sB = b1 ? q0 : q1;
        f32x2 v  = (b1 ? q1 : q0) + shfl_xor2(sB, 2);
        // steps C, D: plain reduce over remaining lane bits.
        v += shfl_xor2(v, 4);
        v += shfl_xor2(v, 8);
        // lane holds full row-sum (over this wave's 64 cols) for
        // row = i_w + ti*16 + quad*4 + (lrow&3), duplicated over lrow>>2.
        if (lrow < 4)
            rowSum[vR][i_w + ti * 16 + quad * 4 + lrow] = v;
    }

    if (!diag) {
        #pragma unroll
        for (int tj = 0; tj < 4; ++tj) {
            f32x2 cv = csum[tj];
            cv += shfl_xor2(cv, 16);
            cv += shfl_xor2(cv, 32);
            if (quad == 0)
                colSum[vC][j_w + tj * 16 + lrow] =
                    (f32x2){cv[0], cv[1] - cv[0]};
        }
    }
    __syncthreads();

    if (tid < 128) {
        f32x2 a = rowSum[0][tid];
        f32x2 b = rowSum[1][tid];
        P[(size_t)bj * BN + i0 + tid] = a[0] + b[0];
        N[(size_t)bj * BN + i0 + tid] = a[1] + b[1];
    } else if (!diag) {
        int c2 = tid - 128;
        f32x2 a = colSum[0][c2];
        f32x2 b = colSum[1][c2];
        P[(size_t)bi * BN + j0 + c2] = a[0] + b[0];
        N[(size_t)bi * BN + j0 + c2] = a[1] + b[1];
    }
}

// Fused tail: 32 blocks x 256. Per-block LDS histogram, per-row partial
// reduce + loss, one atomicAdd of the pre-scaled block sum into out[0].
__global__ __launch_bounds__(256) void reduce_finalize_kernel(
        const int* __restrict__ labels, const float* __restrict__ P,
        const float* __restrict__ N, float* __restrict__ out) {
    __shared__ int cnt[128];
    __shared__ float wsum[4];
    int tid = threadIdx.x;
    if (tid < 128) cnt[tid] = 0;
    __syncthreads();
    for (int i = tid; i < BN; i += 256) atomicAdd(&cnt[labels[i]], 1);
    __syncthreads();

    int i = blockIdx.x * 256 + tid;
    float p = 0.f, n = 0.f;
    #pragma unroll 8
    for (int c = 0; c < NB; ++c) {
        p += P[(size_t)c * BN + i];
        n += N[(size_t)c * BN + i];
    }
    int   cl = cnt[labels[i]];
    float pm = p / fmaxf((float)(cl - 1), 1.0f);
    float nm = n / fmaxf((float)(BN - cl), 1.0f);
    float v  = ((cl - 1 > 0) && (BN - cl > 0))
                   ? -logf(pm / (pm + nm + EPSF)) : 0.0f;
    v *= (1.0f / (float)BN);
    #pragma unroll
    for (int m = 1; m < 64; m <<= 1) v += __shfl_xor(v, m, 64);
    if ((tid & 63) == 0) wsum[tid >> 6] = v;
    __syncthreads();
    if (tid == 0)
        atomicAdd(out, wsum[0] + wsum[1] + wsum[2] + wsum[3]);
}

extern "C" void kernel_launch(void* const* d_in, const int* in_sizes, int n_in,
                              void* d_out, int out_size, void* d_ws, size_t ws_size,
                              hipStream_t stream) {
    const float* emb   = (const float*)d_in[0];
    const int* labels  = (const int*)d_in[1];
    float* out         = (float*)d_out;

    // ws layout: E (8 MB reserved; fp8 uses 4) | P (2 MB) | N (2 MB)
    unsigned char* E   = (unsigned char*)d_ws;
    float* P           = (float*)((char*)d_ws + (size_t)BN * DIM * 2);
    float* N           = P + (size_t)NB * BN;

    normalize_kernel<<<BN / 4, 256, 0, stream>>>(emb, E, out);
    gemm_epi_kernel<<<NTILES, 256, 0, stream>>>(E, labels, P, N);
    reduce_finalize_kernel<<<32, 256, 0, stream>>>(labels, P, N, out);
}

// Round 4
// 116.448 us; speedup vs baseline: 1.3316x; 1.2965x over previous
//
#include <hip/hip_runtime.h>
#include <hip/hip_bf16.h>

#define BN 8192
#define DIM 512
#define NB  64            // BN / 128 block-rows
#define NTILES 2080       // NB*(NB+1)/2 upper-triangle tiles
#define EPSF 1e-8f

using v8i   = __attribute__((ext_vector_type(8))) int;
using v4i   = __attribute__((ext_vector_type(4))) int;
using f32x4 = __attribute__((ext_vector_type(4))) float;

// Native exp2 (single v_exp_f32); fallback keeps exact semantics.
#if __has_builtin(__builtin_amdgcn_exp2f)
#define EXP2F(x) __builtin_amdgcn_exp2f(x)
#else
#define EXP2F(x) __expf((x) * 0.69314718055994531f)
#endif

// Async global->LDS, 16 B per lane, dest = uniform base + lane*16.
__device__ __forceinline__ void async_copy16(const void* g, void* l) {
    __builtin_amdgcn_global_load_lds(
        (const __attribute__((address_space(1))) void*)g,
        (__attribute__((address_space(3))) void*)l,
        16, 0, 0);
}

// One wave per row: L2-normalize, x4 pre-scale, fp8 e4m3; out[0] and the
// global label-count array zeroed by block 0 (cnt is filled by gemm's diag
// blocks, read by finalize -- all stream-ordered).
__global__ __launch_bounds__(256) void normalize_kernel(
        const float* __restrict__ emb, unsigned char* __restrict__ E,
        int* __restrict__ cntG, float* __restrict__ out) {
    if (blockIdx.x == 0) {
        if (threadIdx.x == 0) out[0] = 0.f;
        if (threadIdx.x < 128) cntG[threadIdx.x] = 0;
    }
    int lane = threadIdx.x & 63;
    int row  = blockIdx.x * 4 + (threadIdx.x >> 6);
    const float4* src = (const float4*)(emb + (size_t)row * DIM);
    float4 a = src[lane];
    float4 b = src[lane + 64];
    float ss = a.x*a.x + a.y*a.y + a.z*a.z + a.w*a.w
             + b.x*b.x + b.y*b.y + b.z*b.z + b.w*b.w;
    #pragma unroll
    for (int m = 1; m < 64; m <<= 1) ss += __shfl_xor(ss, m, 64);
    float s4 = 4.0f / fmaxf(sqrtf(ss), 1e-12f);
    int pa = __builtin_amdgcn_cvt_pk_fp8_f32(a.x*s4, a.y*s4, 0, false);
    pa     = __builtin_amdgcn_cvt_pk_fp8_f32(a.z*s4, a.w*s4, pa, true);
    int pb = __builtin_amdgcn_cvt_pk_fp8_f32(b.x*s4, b.y*s4, 0, false);
    pb     = __builtin_amdgcn_cvt_pk_fp8_f32(b.z*s4, b.w*s4, pb, true);
    unsigned char* rowp = E + (size_t)row * DIM;
    ((unsigned*)rowp)[lane]         = (unsigned)pa;
    ((unsigned*)(rowp + 256))[lane] = (unsigned)pb;
}

// Upper-triangle 128x128 tiles, 1D grid (2080), triangular decode.
// fp8 MX MFMA 16x16x128. Round-1 proven structure with one change: A is
// staged TRIPLE-buffered, 2 chunks ahead (BK=128, 3 x 16 KB), so the
// barrier at step k waits on a stage issued a full iteration earlier --
// stage latency is covered by an entire k-step of MFMA+loads instead of
// partially. Counted vmcnt (never 0 in-loop) keeps B prefetch + next
// stage in flight across barriers. sched_barrier(0) fences pin VMEM issue
// order (stage before B) so the vmcnt counts are sound.
// Occupancy note: unified regs ~88 VGPR + 64 AGPR = 152 -> 3 waves/SIMD
// (512/152); LDS 50176 -> 3 blocks/CU. Matched caps -- do NOT add live
// state to the epilogue (round-3 lesson: 196 regs -> 2 waves -> +40% dur).
__global__ __launch_bounds__(256) void gemm_epi_kernel(
        const unsigned char* __restrict__ E, const int* __restrict__ labels,
        int* __restrict__ cntG, float* __restrict__ P, float* __restrict__ N) {
    // smem: A triple-buf (49152 B) overlaid with rowBuf [2][128][17]f2
    // (34816 B) + colBuf [2][128][5]f2 (10240 B) = 45056 B -> union 49152.
    __shared__ __attribute__((aligned(16))) unsigned char smem[49152];
    __shared__ int labI[128];
    __shared__ int labJ[128];

    int t  = blockIdx.x;
    int bi = (int)(64.5f - sqrtf(64.5f * 64.5f - 2.0f * (float)t));
    while (64 * (bi + 1) - ((bi + 1) * bi) / 2 <= t) ++bi;
    while (64 * bi - (bi * (bi - 1)) / 2 > t) --bi;
    int bj = bi + (t - (64 * bi - (bi * (bi - 1)) / 2));
    const bool diag = (bi == bj);
    const int i0 = bi * 128;
    const int j0 = bj * 128;

    const int tid  = threadIdx.x;
    const int wave = tid >> 6;
    const int lane = tid & 63;
    const int quad = lane >> 4;
    const int lrow = lane & 15;
    const int i_w  = (wave >> 1) * 64;
    const int j_w  = (wave & 1) * 64;

    if (tid < 128)       labI[tid]       = labels[i0 + tid];
    else                 labJ[tid - 128] = labels[j0 + tid - 128];
    // Diag blocks build the global label histogram (64 blocks x 128 rows
    // covers every row exactly once). Off the critical path.
    if (diag && tid < 128) atomicAdd(&cntG[labels[i0 + tid]], 1);

    unsigned char* As = smem;                     // [3][128][128]
    float2* rowBuf = (float2*)smem;               // [2][128][17]
    float2* colBuf = (float2*)(smem + 34816);     // [2][128][5]
    const int vR = wave & 1;
    const int vC = wave >> 1;

    f32x4 acc[4][4];
    #pragma unroll
    for (int a = 0; a < 4; ++a)
        #pragma unroll
        for (int b = 0; b < 4; ++b)
            acc[a][b] = (f32x4){0.f, 0.f, 0.f, 0.f};

    const v4i* bptr[4];
    #pragma unroll
    for (int tj = 0; tj < 4; ++tj)
        bptr[tj] = (const v4i*)(E +
            (size_t)(j0 + j_w + tj * 16 + lrow) * DIM + quad * 32);

    // Staging lane constants: each wave covers rows [wave*32, wave*32+32),
    // 4 calls x 8 rows; lane l -> row (l>>3), LDS chunk l&7 holds global
    // chunk (l&7)^(l>>3)  (row&7 == l>>3 since bases are multiples of 8).
    const int stRow = lane >> 3;
    const int stChk = (lane & 7) ^ stRow;
    const unsigned char* gA = E + (size_t)(i0 + wave * 32 + stRow) * DIM
                                + stChk * 16;
    const int sw = lrow & 7;

    // Prologue: issue stage(c0), stage(c1), then B(0) prefetch; retire only
    // c0 (vmcnt(12) leaves c1's 4 + B0's 8 in flight), barrier.
    #pragma unroll
    for (int h = 0; h < 4; ++h)
        async_copy16(gA + (size_t)h * 8 * DIM,
                     As + (size_t)(wave * 32 + h * 8) * 128);
    __builtin_amdgcn_sched_barrier(0);
    #pragma unroll
    for (int h = 0; h < 4; ++h)
        async_copy16(gA + (size_t)h * 8 * DIM + 128,
                     As + 16384 + (size_t)(wave * 32 + h * 8) * 128);
    __builtin_amdgcn_sched_barrier(0);

    v8i bf[2][4];
    #pragma unroll
    for (int tj = 0; tj < 4; ++tj) {      // prefetch B for k=0
        ((v4i*)&bf[0][tj])[0] = bptr[tj][0];
        ((v4i*)&bf[0][tj])[1] = bptr[tj][1];
    }
    asm volatile("s_waitcnt vmcnt(12)" ::: "memory");
    __builtin_amdgcn_s_barrier();

    #pragma unroll
    for (int k = 0; k < 4; ++k) {
        const int cur = k & 1;
        unsigned char* bufC = As + (size_t)(k % 3) * 16384;
        if (k < 2) {                      // issue stage(k+2), 2 ahead
            unsigned char* bufN = As + (size_t)((k + 2) % 3) * 16384;
            #pragma unroll
            for (int h = 0; h < 4; ++h)
                async_copy16(gA + (size_t)h * 8 * DIM + (k + 2) * 128,
                             bufN + (size_t)(wave * 32 + h * 8) * 128);
            __builtin_amdgcn_sched_barrier(0);   // keep stage before B loads
        }
        v8i af[4];
        #pragma unroll
        for (int ti = 0; ti < 4; ++ti) {
            int r  = i_w + ti * 16 + lrow;
            const v4i* rp = (const v4i*)(bufC + (size_t)r * 128);
            ((v4i*)&af[ti])[0] = rp[(quad * 2) ^ sw];
            ((v4i*)&af[ti])[1] = rp[(quad * 2 + 1) ^ sw];
        }
        if (k < 3) {                      // prefetch next k's B
            #pragma unroll
            for (int tj = 0; tj < 4; ++tj) {
                ((v4i*)&bf[cur ^ 1][tj])[0] = bptr[tj][(k + 1) * 8];
                ((v4i*)&bf[cur ^ 1][tj])[1] = bptr[tj][(k + 1) * 8 + 1];
            }
        }
        #pragma unroll
        for (int ti = 0; ti < 4; ++ti)
            #pragma unroll
            for (int tj = 0; tj < 4; ++tj)
                acc[ti][tj] =
                    __builtin_amdgcn_mfma_scale_f32_16x16x128_f8f6f4(
                        af[ti], bf[cur][tj], acc[ti][tj],
                        0, 0,                 // fp8 e4m3 / e4m3
                        0, 0x7F7F7F7F,        // A scale = 1.0
                        0, 0x7F7F7F7F);       // B scale = 1.0
        // Barrier k guards chunk k+1 (staged a full iteration ago).
        // Queue (oldest->new): stage(k+1)4 | stage(k+2)4, B(k+1)8.
        if (k == 0 || k == 1) {
            asm volatile("s_waitcnt vmcnt(12)" ::: "memory");
            __builtin_amdgcn_s_barrier();
        } else if (k == 2) {
            asm volatile("s_waitcnt vmcnt(8)" ::: "memory");
            __builtin_amdgcn_s_barrier();
        }
    }
    __syncthreads();      // As dead -> reduction buffers writable

    // Epilogue (round-1 proven, 88-VGPR). C/D: col = lane&15,
    // row = quad*4 + reg. acc = 16*S. w = exp(S-1) = exp2(acc*K1 + K2).
    const float K1 = 0.0901619783824569f;    // log2(e)/16
    const float K2 = -1.4426950408889634f;   // -log2(e)
    if (!diag) {
        float psC[4] = {0.f, 0.f, 0.f, 0.f};
        float tsC[4] = {0.f, 0.f, 0.f, 0.f};
        #pragma unroll
        for (int ti = 0; ti < 4; ++ti) {
            #pragma unroll
            for (int reg = 0; reg < 4; ++reg) {
                int irow = i_w + ti * 16 + quad * 4 + reg;
                int li   = labI[irow];
                float ps = 0.f, ts = 0.f;
                #pragma unroll
                for (int tj = 0; tj < 4; ++tj) {
                    int jcol = j_w + tj * 16 + lrow;
                    float w  = EXP2F(fmaf(acc[ti][tj][reg], K1, K2));
                    float wp = (li == labJ[jcol]) ? w : 0.f;
                    ps += wp;  ts += w;
                    psC[tj] += wp;  tsC[tj] += w;
                }
                rowBuf[(size_t)(vR * 128 + irow) * 17 + lrow] =
                    (float2){ps, ts - ps};
            }
        }
        #pragma unroll
        for (int tj = 0; tj < 4; ++tj) {
            int jcol = j_w + tj * 16 + lrow;
            colBuf[(size_t)(vC * 128 + jcol) * 5 + quad] =
                (float2){psC[tj], tsC[tj] - psC[tj]};
        }
    } else {
        // Diag tile: self pair (irow == jcol) excluded from pos exactly;
        // col sums unused (row path covers the full square).
        #pragma unroll
        for (int ti = 0; ti < 4; ++ti) {
            #pragma unroll
            for (int reg = 0; reg < 4; ++reg) {
                int irow = i_w + ti * 16 + quad * 4 + reg;
                int li   = labI[irow];
                float ps = 0.f, ts = 0.f, sf = 0.f;
                #pragma unroll
                for (int tj = 0; tj < 4; ++tj) {
                    int jcol = j_w + tj * 16 + lrow;
                    float w  = EXP2F(fmaf(acc[ti][tj][reg], K1, K2));
                    float wp = (li == labJ[jcol]) ? w : 0.f;
                    float wd = (irow == jcol) ? w : 0.f;
                    ps += wp;  ts += w;  sf += wd;
                }
                rowBuf[(size_t)(vR * 128 + irow) * 17 + lrow] =
                    (float2){ps - sf, ts - ps};
            }
        }
    }
    __syncthreads();

    if (tid < 128) {
        const float2* a = rowBuf + (size_t)tid * 17;
        const float2* b = rowBuf + (size_t)(128 + tid) * 17;
        float sp = 0.f, sn = 0.f;
        #pragma unroll
        for (int u = 0; u < 16; ++u) {
            sp += a[u].x + b[u].x;
            sn += a[u].y + b[u].y;
        }
        P[(size_t)bj * BN + i0 + tid] = sp;
        N[(size_t)bj * BN + i0 + tid] = sn;
    } else if (!diag) {
        int c2 = tid - 128;
        const float2* a = colBuf + (size_t)c2 * 5;
        const float2* b = colBuf + (size_t)(128 + c2) * 5;
        float sp = 0.f, sn = 0.f;
        #pragma unroll
        for (int u = 0; u < 4; ++u) {
            sp += a[u].x + b[u].x;
            sn += a[u].y + b[u].y;
        }
        P[(size_t)bi * BN + j0 + c2] = sp;
        N[(size_t)bi * BN + j0 + c2] = sn;
    }
}

// Fused tail: 128 blocks x 256. Each block owns 64 rows; the 4 waves split
// the 64 column-blocks (16 strided, coalesced 256B/wave), LDS combine,
// per-row loss (histogram read from precomputed global cnt), one
// atomicAdd of the pre-scaled block sum into out[0].
__global__ __launch_bounds__(256) void reduce_finalize_kernel(
        const int* __restrict__ labels, const float* __restrict__ P,
        const float* __restrict__ N, const int* __restrict__ cntG,
        float* __restrict__ out) {
    __shared__ float2 buf[4][64];
    int tid = threadIdx.x;
    int r = tid & 63, w = tid >> 6;
    int i = blockIdx.x * 64 + r;
    float p = 0.f, n = 0.f;
    #pragma unroll
    for (int u = 0; u < 16; ++u) {
        int c = w + u * 4;
        p += P[(size_t)c * BN + i];
        n += N[(size_t)c * BN + i];
    }
    buf[w][r] = (float2){p, n};
    __syncthreads();
    if (tid < 64) {
        float2 s0 = buf[0][r], s1 = buf[1][r], s2 = buf[2][r], s3 = buf[3][r];
        p = s0.x + s1.x + s2.x + s3.x;
        n = s0.y + s1.y + s2.y + s3.y;
        int   cl = cntG[labels[i]];
        float pm = p / fmaxf((float)(cl - 1), 1.0f);
        float nm = n / fmaxf((float)(BN - cl), 1.0f);
        float v  = ((cl - 1 > 0) && (BN - cl > 0))
                       ? -logf(pm / (pm + nm + EPSF)) : 0.0f;
        v *= (1.0f / (float)BN);
        #pragma unroll
        for (int m = 1; m < 64; m <<= 1) v += __shfl_xor(v, m, 64);
        if (r == 0) atomicAdd(out, v);
    }
}

extern "C" void kernel_launch(void* const* d_in, const int* in_sizes, int n_in,
                              void* d_out, int out_size, void* d_ws, size_t ws_size,
                              hipStream_t stream) {
    const float* emb   = (const float*)d_in[0];
    const int* labels  = (const int*)d_in[1];
    float* out         = (float*)d_out;

    // ws layout: E (8 MB reserved; fp8 uses 4, cnt lives at +4 MB) |
    // P (2 MB) | N (2 MB)
    unsigned char* E   = (unsigned char*)d_ws;
    int* cntG          = (int*)((char*)d_ws + (size_t)BN * DIM);
    float* P           = (float*)((char*)d_ws + (size_t)BN * DIM * 2);
    float* N           = P + (size_t)NB * BN;

    normalize_kernel<<<BN / 4, 256, 0, stream>>>(emb, E, cntG, out);
    gemm_epi_kernel<<<NTILES, 256, 0, stream>>>(E, labels, cntG, P, N);
    reduce_finalize_kernel<<<128, 256, 0, stream>>>(labels, P, N, cntG, out);
}

// Round 5
// 115.353 us; speedup vs baseline: 1.3443x; 1.0095x over previous
//
#include <hip/hip_runtime.h>
#include <hip/hip_bf16.h>

#define BN 8192
#define DIM 512
#define NB  64            // BN / 128 block-rows
#define NTILES 2080       // NB*(NB+1)/2 upper-triangle tiles
#define EPSF 1e-8f

using v8i   = __attribute__((ext_vector_type(8))) int;
using v4i   = __attribute__((ext_vector_type(4))) int;
using f32x4 = __attribute__((ext_vector_type(4))) float;

// Native exp2 (single v_exp_f32); fallback keeps exact semantics.
#if __has_builtin(__builtin_amdgcn_exp2f)
#define EXP2F(x) __builtin_amdgcn_exp2f(x)
#else
#define EXP2F(x) __expf((x) * 0.69314718055994531f)
#endif

// Async global->LDS, 16 B per lane, dest = uniform base + lane*16.
__device__ __forceinline__ void async_copy16(const void* g, void* l) {
    __builtin_amdgcn_global_load_lds(
        (const __attribute__((address_space(1))) void*)g,
        (__attribute__((address_space(3))) void*)l,
        16, 0, 0);
}

// One wave per row: L2-normalize, x4 pre-scale, fp8 e4m3; out[0] and the
// global label-count array zeroed by block 0 (cnt is filled by gemm's diag
// blocks, read by finalize -- all stream-ordered).
__global__ __launch_bounds__(256) void normalize_kernel(
        const float* __restrict__ emb, unsigned char* __restrict__ E,
        int* __restrict__ cntG, float* __restrict__ out) {
    if (blockIdx.x == 0) {
        if (threadIdx.x == 0) out[0] = 0.f;
        if (threadIdx.x < 128) cntG[threadIdx.x] = 0;
    }
    int lane = threadIdx.x & 63;
    int row  = blockIdx.x * 4 + (threadIdx.x >> 6);
    const float4* src = (const float4*)(emb + (size_t)row * DIM);
    float4 a = src[lane];
    float4 b = src[lane + 64];
    float ss = a.x*a.x + a.y*a.y + a.z*a.z + a.w*a.w
             + b.x*b.x + b.y*b.y + b.z*b.z + b.w*b.w;
    #pragma unroll
    for (int m = 1; m < 64; m <<= 1) ss += __shfl_xor(ss, m, 64);
    float s4 = 4.0f / fmaxf(sqrtf(ss), 1e-12f);
    int pa = __builtin_amdgcn_cvt_pk_fp8_f32(a.x*s4, a.y*s4, 0, false);
    pa     = __builtin_amdgcn_cvt_pk_fp8_f32(a.z*s4, a.w*s4, pa, true);
    int pb = __builtin_amdgcn_cvt_pk_fp8_f32(b.x*s4, b.y*s4, 0, false);
    pb     = __builtin_amdgcn_cvt_pk_fp8_f32(b.z*s4, b.w*s4, pb, true);
    unsigned char* rowp = E + (size_t)row * DIM;
    ((unsigned*)rowp)[lane]         = (unsigned)pa;
    ((unsigned*)(rowp + 256))[lane] = (unsigned)pb;
}

// Upper-triangle 128x128 tiles, 1D grid (2080), triangular decode.
// fp8 MX MFMA 16x16x128. NEW: 512-thread blocks (8 waves), wave (vC,vQ)
// owns a 64x32 output (4x2 of 16x16). Register budget: acc 32 AGPR +
// B-dbuf 32 VGPR + A-frags 32 transient => ~112 unified, enforced by
// __launch_bounds__(512,4) -> 4 waves/SIMD (was 3 at 152 regs) and 2
// blocks/CU: +33% resident waves to cover the ~75% no-issue cycles
// measured in round 4. Pipeline = round-4 proven scheme (A triple-buf
// BK=128, stage 2 ahead, counted vmcnt never 0 in-loop, sched_barrier
// fences pin VMEM order). Counts recomputed for this shape: stage = 2
// instrs/wave, B-set = 4 instrs/wave.
__global__ __launch_bounds__(512, 4) void gemm_epi_kernel(
        const unsigned char* __restrict__ E, const int* __restrict__ labels,
        int* __restrict__ cntG, float* __restrict__ P, float* __restrict__ N) {
    // smem: A triple-buf (49152 B) overlaid with rowBuf [4][128][17]f2
    // (69632 B) + colBuf [4][2][128]f2 (8192 B) = 77824 B union.
    __shared__ __attribute__((aligned(16))) unsigned char smem[77824];
    __shared__ int labI[128];
    __shared__ int labJ[128];

    int t  = blockIdx.x;
    int bi = (int)(64.5f - sqrtf(64.5f * 64.5f - 2.0f * (float)t));
    while (64 * (bi + 1) - ((bi + 1) * bi) / 2 <= t) ++bi;
    while (64 * bi - (bi * (bi - 1)) / 2 > t) --bi;
    int bj = bi + (t - (64 * bi - (bi * (bi - 1)) / 2));
    const bool diag = (bi == bj);
    const int i0 = bi * 128;
    const int j0 = bj * 128;

    const int tid  = threadIdx.x;
    const int wave = tid >> 6;          // 0..7
    const int lane = tid & 63;
    const int quad = lane >> 4;
    const int lrow = lane & 15;
    const int vC   = wave >> 2;         // i-half   (0..1)
    const int vQ   = wave & 3;          // j-quarter(0..3)
    const int i_w  = vC * 64;
    const int j_w  = vQ * 32;

    if (tid < 128)        labI[tid]       = labels[i0 + tid];
    else if (tid < 256)   labJ[tid - 128] = labels[j0 + tid - 128];
    // Diag blocks build the global label histogram (64 blocks x 128 rows
    // covers every row exactly once). Issued before staging; retires with
    // S0 at the prologue vmcnt.
    if (diag && tid < 128) atomicAdd(&cntG[labels[i0 + tid]], 1);

    unsigned char* As = smem;                     // [3][128][128]
    float2* rowBuf = (float2*)smem;               // [4][128][17]
    float2* colBuf = (float2*)(smem + 69632);     // [4][2][128]

    f32x4 acc[4][2];
    #pragma unroll
    for (int a = 0; a < 4; ++a)
        #pragma unroll
        for (int b = 0; b < 2; ++b)
            acc[a][b] = (f32x4){0.f, 0.f, 0.f, 0.f};

    const v4i* bptr[2];
    #pragma unroll
    for (int tj = 0; tj < 2; ++tj)
        bptr[tj] = (const v4i*)(E +
            (size_t)(j0 + j_w + tj * 16 + lrow) * DIM + quad * 32);

    // Staging lane constants: each wave covers rows [wave*16, wave*16+16),
    // 2 calls x 8 rows; lane l -> row (l>>3), LDS chunk l&7 holds global
    // chunk (l&7)^(l>>3)  (row&7 == l>>3 since bases are multiples of 8).
    const int stRow = lane >> 3;
    const int stChk = (lane & 7) ^ stRow;
    const unsigned char* gA = E + (size_t)(i0 + wave * 16 + stRow) * DIM
                                + stChk * 16;
    const int sw = lrow & 7;

    // Prologue: issue stage(c0) 2, stage(c1) 2, then B(0) prefetch 4;
    // retire c0 (+diag atomic): vmcnt(6) leaves c1's 2 + B0's 4.
    // lgkmcnt(0) drains the label ds_writes before the barrier.
    #pragma unroll
    for (int h = 0; h < 2; ++h)
        async_copy16(gA + (size_t)h * 8 * DIM,
                     As + (size_t)(wave * 16 + h * 8) * 128);
    __builtin_amdgcn_sched_barrier(0);
    #pragma unroll
    for (int h = 0; h < 2; ++h)
        async_copy16(gA + (size_t)h * 8 * DIM + 128,
                     As + 16384 + (size_t)(wave * 16 + h * 8) * 128);
    __builtin_amdgcn_sched_barrier(0);

    v8i bf[2][2];
    #pragma unroll
    for (int tj = 0; tj < 2; ++tj) {      // prefetch B for k=0
        ((v4i*)&bf[0][tj])[0] = bptr[tj][0];
        ((v4i*)&bf[0][tj])[1] = bptr[tj][1];
    }
    asm volatile("s_waitcnt vmcnt(6) lgkmcnt(0)" ::: "memory");
    __builtin_amdgcn_s_barrier();

    #pragma unroll
    for (int k = 0; k < 4; ++k) {
        const int cur = k & 1;
        unsigned char* bufC = As + (size_t)(k % 3) * 16384;
        if (k < 2) {                      // issue stage(k+2), 2 ahead
            unsigned char* bufN = As + (size_t)((k + 2) % 3) * 16384;
            #pragma unroll
            for (int h = 0; h < 2; ++h)
                async_copy16(gA + (size_t)h * 8 * DIM + (k + 2) * 128,
                             bufN + (size_t)(wave * 16 + h * 8) * 128);
            __builtin_amdgcn_sched_barrier(0);   // keep stage before B loads
        }
        v8i af[4];
        #pragma unroll
        for (int ti = 0; ti < 4; ++ti) {
            int r  = i_w + ti * 16 + lrow;
            const v4i* rp = (const v4i*)(bufC + (size_t)r * 128);
            ((v4i*)&af[ti])[0] = rp[(quad * 2) ^ sw];
            ((v4i*)&af[ti])[1] = rp[(quad * 2 + 1) ^ sw];
        }
        if (k < 3) {                      // prefetch next k's B
            #pragma unroll
            for (int tj = 0; tj < 2; ++tj) {
                ((v4i*)&bf[cur ^ 1][tj])[0] = bptr[tj][(k + 1) * 8];
                ((v4i*)&bf[cur ^ 1][tj])[1] = bptr[tj][(k + 1) * 8 + 1];
            }
        }
        #pragma unroll
        for (int ti = 0; ti < 4; ++ti)
            #pragma unroll
            for (int tj = 0; tj < 2; ++tj)
                acc[ti][tj] =
                    __builtin_amdgcn_mfma_scale_f32_16x16x128_f8f6f4(
                        af[ti], bf[cur][tj], acc[ti][tj],
                        0, 0,                 // fp8 e4m3 / e4m3
                        0, 0x7F7F7F7F,        // A scale = 1.0
                        0, 0x7F7F7F7F);       // B scale = 1.0
        // Barrier k guards chunk k+1 (staged a full iteration ago).
        // Queue (oldest->new): stage(k+1)2 | stage(k+2)2, B(k+1)4.
        if (k == 0 || k == 1) {
            asm volatile("s_waitcnt vmcnt(6)" ::: "memory");
            __builtin_amdgcn_s_barrier();
        } else if (k == 2) {
            asm volatile("s_waitcnt vmcnt(4)" ::: "memory");
            __builtin_amdgcn_s_barrier();
        }
    }
    __syncthreads();      // As dead -> reduction buffers writable

    // Epilogue. C/D: col = lane&15, row = quad*4 + reg. acc = 16*S.
    // w = exp(S-1) = exp2(acc*K1 + K2). 32 elements/thread.
    const float K1 = 0.0901619783824569f;    // log2(e)/16
    const float K2 = -1.4426950408889634f;   // -log2(e)
    if (!diag) {
        float psC[2] = {0.f, 0.f};
        float tsC[2] = {0.f, 0.f};
        #pragma unroll
        for (int ti = 0; ti < 4; ++ti) {
            #pragma unroll
            for (int reg = 0; reg < 4; ++reg) {
                int irow = i_w + ti * 16 + quad * 4 + reg;
                int li   = labI[irow];
                float ps = 0.f, ts = 0.f;
                #pragma unroll
                for (int tj = 0; tj < 2; ++tj) {
                    int jcol = j_w + tj * 16 + lrow;
                    float w  = EXP2F(fmaf(acc[ti][tj][reg], K1, K2));
                    float wp = (li == labJ[jcol]) ? w : 0.f;
                    ps += wp;  ts += w;
                    psC[tj] += wp;  tsC[tj] += w;
                }
                rowBuf[(size_t)(vQ * 128 + irow) * 17 + lrow] =
                    (float2){ps, ts - ps};
            }
        }
        #pragma unroll
        for (int tj = 0; tj < 2; ++tj) {
            int jcol = j_w + tj * 16 + lrow;
            colBuf[(size_t)(quad * 2 + vC) * 128 + jcol] =
                (float2){psC[tj], tsC[tj] - psC[tj]};
        }
    } else {
        // Diag tile: self pair (irow == jcol) excluded from pos exactly;
        // col sums unused (row path covers the full square).
        #pragma unroll
        for (int ti = 0; ti < 4; ++ti) {
            #pragma unroll
            for (int reg = 0; reg < 4; ++reg) {
                int irow = i_w + ti * 16 + quad * 4 + reg;
                int li   = labI[irow];
                float ps = 0.f, ts = 0.f, sf = 0.f;
                #pragma unroll
                for (int tj = 0; tj < 2; ++tj) {
                    int jcol = j_w + tj * 16 + lrow;
                    float w  = EXP2F(fmaf(acc[ti][tj][reg], K1, K2));
                    float wp = (li == labJ[jcol]) ? w : 0.f;
                    float wd = (irow == jcol) ? w : 0.f;
                    ps += wp;  ts += w;  sf += wd;
                }
                rowBuf[(size_t)(vQ * 128 + irow) * 17 + lrow] =
                    (float2){ps - sf, ts - ps};
            }
        }
    }
    __syncthreads();

    if (tid < 128) {
        float sp = 0.f, sn = 0.f;
        #pragma unroll
        for (int vq = 0; vq < 4; ++vq) {
            const float2* a = rowBuf + (size_t)(vq * 128 + tid) * 17;
            #pragma unroll
            for (int u = 0; u < 16; ++u) {
                sp += a[u].x;
                sn += a[u].y;
            }
        }
        P[(size_t)bj * BN + i0 + tid] = sp;
        N[(size_t)bj * BN + i0 + tid] = sn;
    } else if (tid < 256 && !diag) {
        int c2 = tid - 128;
        float sp = 0.f, sn = 0.f;
        #pragma unroll
        for (int s = 0; s < 8; ++s) {
            float2 a = colBuf[(size_t)s * 128 + c2];
            sp += a.x;
            sn += a.y;
        }
        P[(size_t)bi * BN + j0 + c2] = sp;
        N[(size_t)bi * BN + j0 + c2] = sn;
    }
}

// Fused tail: 128 blocks x 256. Each block owns 64 rows; the 4 waves split
// the 64 column-blocks (16 strided, coalesced 256B/wave), LDS combine,
// per-row loss (histogram read from precomputed global cnt), one
// atomicAdd of the pre-scaled block sum into out[0].
__global__ __launch_bounds__(256) void reduce_finalize_kernel(
        const int* __restrict__ labels, const float* __restrict__ P,
        const float* __restrict__ N, const int* __restrict__ cntG,
        float* __restrict__ out) {
    __shared__ float2 buf[4][64];
    int tid = threadIdx.x;
    int r = tid & 63, w = tid >> 6;
    int i = blockIdx.x * 64 + r;
    float p = 0.f, n = 0.f;
    #pragma unroll
    for (int u = 0; u < 16; ++u) {
        int c = w + u * 4;
        p += P[(size_t)c * BN + i];
        n += N[(size_t)c * BN + i];
    }
    buf[w][r] = (float2){p, n};
    __syncthreads();
    if (tid < 64) {
        float2 s0 = buf[0][r], s1 = buf[1][r], s2 = buf[2][r], s3 = buf[3][r];
        p = s0.x + s1.x + s2.x + s3.x;
        n = s0.y + s1.y + s2.y + s3.y;
        int   cl = cntG[labels[i]];
        float pm = p / fmaxf((float)(cl - 1), 1.0f);
        float nm = n / fmaxf((float)(BN - cl), 1.0f);
        float v  = ((cl - 1 > 0) && (BN - cl > 0))
                       ? -logf(pm / (pm + nm + EPSF)) : 0.0f;
        v *= (1.0f / (float)BN);
        #pragma unroll
        for (int m = 1; m < 64; m <<= 1) v += __shfl_xor(v, m, 64);
        if (r == 0) atomicAdd(out, v);
    }
}

extern "C" void kernel_launch(void* const* d_in, const int* in_sizes, int n_in,
                              void* d_out, int out_size, void* d_ws, size_t ws_size,
                              hipStream_t stream) {
    const float* emb   = (const float*)d_in[0];
    const int* labels  = (const int*)d_in[1];
    float* out         = (float*)d_out;

    // ws layout: E (8 MB reserved; fp8 uses 4, cnt lives at +4 MB) |
    // P (2 MB) | N (2 MB)
    unsigned char* E   = (unsigned char*)d_ws;
    int* cntG          = (int*)((char*)d_ws + (size_t)BN * DIM);
    float* P           = (float*)((char*)d_ws + (size_t)BN * DIM * 2);
    float* N           = P + (size_t)NB * BN;

    normalize_kernel<<<BN / 4, 256, 0, stream>>>(emb, E, cntG, out);
    gemm_epi_kernel<<<NTILES, 512, 0, stream>>>(E, labels, cntG, P, N);
    reduce_finalize_kernel<<<128, 256, 0, stream>>>(labels, P, N, cntG, out);
}

// Round 6
// 112.452 us; speedup vs baseline: 1.3789x; 1.0258x over previous
//
#include <hip/hip_runtime.h>
#include <hip/hip_bf16.h>

#define BN 8192
#define DIM 512
#define NB  64            // BN / 128 block-rows
#define NTILES 2080       // NB*(NB+1)/2 upper-triangle tiles
#define EPSF 1e-8f

using v8i   = __attribute__((ext_vector_type(8))) int;
using v4i   = __attribute__((ext_vector_type(4))) int;
using f32x4 = __attribute__((ext_vector_type(4))) float;

// Native exp2 (single v_exp_f32); fallback keeps exact semantics.
#if __has_builtin(__builtin_amdgcn_exp2f)
#define EXP2F(x) __builtin_amdgcn_exp2f(x)
#else
#define EXP2F(x) __expf((x) * 0.69314718055994531f)
#endif

// Async global->LDS, 16 B per lane, dest = uniform base + lane*16.
__device__ __forceinline__ void async_copy16(const void* g, void* l) {
    __builtin_amdgcn_global_load_lds(
        (const __attribute__((address_space(1))) void*)g,
        (__attribute__((address_space(3))) void*)l,
        16, 0, 0);
}

// One wave per row: L2-normalize, x4 pre-scale, fp8 e4m3; out[0] and the
// global label-count array zeroed by block 0 (cnt is filled by gemm's diag
// blocks, read by finalize -- all stream-ordered).
__global__ __launch_bounds__(256) void normalize_kernel(
        const float* __restrict__ emb, unsigned char* __restrict__ E,
        int* __restrict__ cntG, float* __restrict__ out) {
    if (blockIdx.x == 0) {
        if (threadIdx.x == 0) out[0] = 0.f;
        if (threadIdx.x < 128) cntG[threadIdx.x] = 0;
    }
    int lane = threadIdx.x & 63;
    int row  = blockIdx.x * 4 + (threadIdx.x >> 6);
    const float4* src = (const float4*)(emb + (size_t)row * DIM);
    float4 a = src[lane];
    float4 b = src[lane + 64];
    float ss = a.x*a.x + a.y*a.y + a.z*a.z + a.w*a.w
             + b.x*b.x + b.y*b.y + b.z*b.z + b.w*b.w;
    #pragma unroll
    for (int m = 1; m < 64; m <<= 1) ss += __shfl_xor(ss, m, 64);
    float s4 = 4.0f / fmaxf(sqrtf(ss), 1e-12f);
    int pa = __builtin_amdgcn_cvt_pk_fp8_f32(a.x*s4, a.y*s4, 0, false);
    pa     = __builtin_amdgcn_cvt_pk_fp8_f32(a.z*s4, a.w*s4, pa, true);
    int pb = __builtin_amdgcn_cvt_pk_fp8_f32(b.x*s4, b.y*s4, 0, false);
    pb     = __builtin_amdgcn_cvt_pk_fp8_f32(b.z*s4, b.w*s4, pb, true);
    unsigned char* rowp = E + (size_t)row * DIM;
    ((unsigned*)rowp)[lane]         = (unsigned)pa;
    ((unsigned*)(rowp + 256))[lane] = (unsigned)pb;
}

// Upper-triangle 128x128 tiles, 1D grid (2080), triangular decode.
// fp8 MX MFMA 16x16x128. 512-thread blocks (8 waves), wave (vC,vQ) owns a
// 64x32 output (4x2 of 16x16).
// NEW (round 6): BARRIER-FREE k-loop. K=512 is only 4 BK=128 chunks, so
// ALL FOUR A-planes (4 x 16 KB) are staged in the prologue; one barrier
// (vmcnt(4): all staging retired, B0 prefetch still in flight) and then
// the k-loop has no barriers and no staging -- each wave streams
// ds_read->MFMA->B-prefetch independently with compiler-tracked register
// waits. Round-5 evidence: +33% occupancy at identical duration => stalls
// were CORRELATED at the per-k-step barriers (one convoy per k-step per
// block). This removes 3 of 4 convoys per block; after the single
// prologue barrier, the 4 waves/SIMD from 2 blocks decorrelate.
// Per-plane XOR swizzle unchanged: LDS chunk p of row r = global chunk
// p^(r&7). LDS union unchanged (A 64 KB overlaid by rowBuf 68 KB +
// colBuf 8 KB = 77824 B) -> still 2 blocks/CU.
__global__ __launch_bounds__(512, 4) void gemm_epi_kernel(
        const unsigned char* __restrict__ E, const int* __restrict__ labels,
        int* __restrict__ cntG, float* __restrict__ P, float* __restrict__ N) {
    // smem: A 4-plane (65536 B) overlaid with rowBuf [4][128][17]f2
    // (69632 B) + colBuf [4][2][128]f2 (8192 B) = 77824 B union.
    __shared__ __attribute__((aligned(16))) unsigned char smem[77824];
    __shared__ int labI[128];
    __shared__ int labJ[128];

    int t  = blockIdx.x;
    int bi = (int)(64.5f - sqrtf(64.5f * 64.5f - 2.0f * (float)t));
    while (64 * (bi + 1) - ((bi + 1) * bi) / 2 <= t) ++bi;
    while (64 * bi - (bi * (bi - 1)) / 2 > t) --bi;
    int bj = bi + (t - (64 * bi - (bi * (bi - 1)) / 2));
    const bool diag = (bi == bj);
    const int i0 = bi * 128;
    const int j0 = bj * 128;

    const int tid  = threadIdx.x;
    const int wave = tid >> 6;          // 0..7
    const int lane = tid & 63;
    const int quad = lane >> 4;
    const int lrow = lane & 15;
    const int vC   = wave >> 2;         // i-half   (0..1)
    const int vQ   = wave & 3;          // j-quarter(0..3)
    const int i_w  = vC * 64;
    const int j_w  = vQ * 32;

    if (tid < 128)        labI[tid]       = labels[i0 + tid];
    else if (tid < 256)   labJ[tid - 128] = labels[j0 + tid - 128];
    // Diag blocks build the global label histogram (64 blocks x 128 rows
    // covers every row exactly once). Issued before staging; retired by
    // the prologue vmcnt (in-order VMEM retirement).
    if (diag && tid < 128) atomicAdd(&cntG[labels[i0 + tid]], 1);

    unsigned char* As = smem;                     // [4][128][128] planes
    float2* rowBuf = (float2*)smem;               // [4][128][17]
    float2* colBuf = (float2*)(smem + 69632);     // [4][2][128]

    f32x4 acc[4][2];
    #pragma unroll
    for (int a = 0; a < 4; ++a)
        #pragma unroll
        for (int b = 0; b < 2; ++b)
            acc[a][b] = (f32x4){0.f, 0.f, 0.f, 0.f};

    const v4i* bptr[2];
    #pragma unroll
    for (int tj = 0; tj < 2; ++tj)
        bptr[tj] = (const v4i*)(E +
            (size_t)(j0 + j_w + tj * 16 + lrow) * DIM + quad * 32);

    // Staging lane constants: each wave covers rows [wave*16, wave*16+16),
    // 2 instrs x 8 rows per plane; lane l -> row (l>>3), LDS chunk l&7
    // holds global chunk (l&7)^(l>>3) (row&7 == l>>3, bases multiple of 8).
    const int stRow = lane >> 3;
    const int stChk = (lane & 7) ^ stRow;
    const unsigned char* gA = E + (size_t)(i0 + wave * 16 + stRow) * DIM
                                + stChk * 16;
    const int sw = lrow & 7;

    // Prologue: stage ALL 4 planes (8 instrs/wave), then B(0) prefetch
    // (4 instrs). vmcnt(4): staging fully retired (older than B0),
    // B0 still in flight. lgkmcnt(0) drains the label ds_writes.
    #pragma unroll
    for (int c = 0; c < 4; ++c)
        #pragma unroll
        for (int h = 0; h < 2; ++h)
            async_copy16(gA + (size_t)h * 8 * DIM + c * 128,
                         As + (size_t)c * 16384
                            + (size_t)(wave * 16 + h * 8) * 128);
    __builtin_amdgcn_sched_barrier(0);   // keep staging before B loads

    v8i bf[2][2];
    #pragma unroll
    for (int tj = 0; tj < 2; ++tj) {      // prefetch B for k=0
        ((v4i*)&bf[0][tj])[0] = bptr[tj][0];
        ((v4i*)&bf[0][tj])[1] = bptr[tj][1];
    }
    asm volatile("s_waitcnt vmcnt(4) lgkmcnt(0)" ::: "memory");
    __builtin_amdgcn_s_barrier();
    // ---- from here to the epilogue sync: NO barriers, NO staging ----

    #pragma unroll
    for (int k = 0; k < 4; ++k) {
        const int cur = k & 1;
        const unsigned char* bufC = As + (size_t)k * 16384;
        v8i af[4];
        #pragma unroll
        for (int ti = 0; ti < 4; ++ti) {
            int r  = i_w + ti * 16 + lrow;
            const v4i* rp = (const v4i*)(bufC + (size_t)r * 128);
            ((v4i*)&af[ti])[0] = rp[(quad * 2) ^ sw];
            ((v4i*)&af[ti])[1] = rp[(quad * 2 + 1) ^ sw];
        }
        if (k < 3) {                      // prefetch next k's B
            #pragma unroll
            for (int tj = 0; tj < 2; ++tj) {
                ((v4i*)&bf[cur ^ 1][tj])[0] = bptr[tj][(k + 1) * 8];
                ((v4i*)&bf[cur ^ 1][tj])[1] = bptr[tj][(k + 1) * 8 + 1];
            }
        }
        #pragma unroll
        for (int ti = 0; ti < 4; ++ti)
            #pragma unroll
            for (int tj = 0; tj < 2; ++tj)
                acc[ti][tj] =
                    __builtin_amdgcn_mfma_scale_f32_16x16x128_f8f6f4(
                        af[ti], bf[cur][tj], acc[ti][tj],
                        0, 0,                 // fp8 e4m3 / e4m3
                        0, 0x7F7F7F7F,        // A scale = 1.0
                        0, 0x7F7F7F7F);       // B scale = 1.0
    }
    __syncthreads();      // all waves done reading As -> overlay writable

    // Epilogue. C/D: col = lane&15, row = quad*4 + reg. acc = 16*S.
    // w = exp(S-1) = exp2(acc*K1 + K2). 32 elements/thread.
    const float K1 = 0.0901619783824569f;    // log2(e)/16
    const float K2 = -1.4426950408889634f;   // -log2(e)
    if (!diag) {
        float psC[2] = {0.f, 0.f};
        float tsC[2] = {0.f, 0.f};
        #pragma unroll
        for (int ti = 0; ti < 4; ++ti) {
            #pragma unroll
            for (int reg = 0; reg < 4; ++reg) {
                int irow = i_w + ti * 16 + quad * 4 + reg;
                int li   = labI[irow];
                float ps = 0.f, ts = 0.f;
                #pragma unroll
                for (int tj = 0; tj < 2; ++tj) {
                    int jcol = j_w + tj * 16 + lrow;
                    float w  = EXP2F(fmaf(acc[ti][tj][reg], K1, K2));
                    float wp = (li == labJ[jcol]) ? w : 0.f;
                    ps += wp;  ts += w;
                    psC[tj] += wp;  tsC[tj] += w;
                }
                rowBuf[(size_t)(vQ * 128 + irow) * 17 + lrow] =
                    (float2){ps, ts - ps};
            }
        }
        #pragma unroll
        for (int tj = 0; tj < 2; ++tj) {
            int jcol = j_w + tj * 16 + lrow;
            colBuf[(size_t)(quad * 2 + vC) * 128 + jcol] =
                (float2){psC[tj], tsC[tj] - psC[tj]};
        }
    } else {
        // Diag tile: self pair (irow == jcol) excluded from pos exactly;
        // col sums unused (row path covers the full square).
        #pragma unroll
        for (int ti = 0; ti < 4; ++ti) {
            #pragma unroll
            for (int reg = 0; reg < 4; ++reg) {
                int irow = i_w + ti * 16 + quad * 4 + reg;
                int li   = labI[irow];
                float ps = 0.f, ts = 0.f, sf = 0.f;
                #pragma unroll
                for (int tj = 0; tj < 2; ++tj) {
                    int jcol = j_w + tj * 16 + lrow;
                    float w  = EXP2F(fmaf(acc[ti][tj][reg], K1, K2));
                    float wp = (li == labJ[jcol]) ? w : 0.f;
                    float wd = (irow == jcol) ? w : 0.f;
                    ps += wp;  ts += w;  sf += wd;
                }
                rowBuf[(size_t)(vQ * 128 + irow) * 17 + lrow] =
                    (float2){ps - sf, ts - ps};
            }
        }
    }
    __syncthreads();

    if (tid < 128) {
        float sp = 0.f, sn = 0.f;
        #pragma unroll
        for (int vq = 0; vq < 4; ++vq) {
            const float2* a = rowBuf + (size_t)(vq * 128 + tid) * 17;
            #pragma unroll
            for (int u = 0; u < 16; ++u) {
                sp += a[u].x;
                sn += a[u].y;
            }
        }
        P[(size_t)bj * BN + i0 + tid] = sp;
        N[(size_t)bj * BN + i0 + tid] = sn;
    } else if (tid < 256 && !diag) {
        int c2 = tid - 128;
        float sp = 0.f, sn = 0.f;
        #pragma unroll
        for (int s = 0; s < 8; ++s) {
            float2 a = colBuf[(size_t)s * 128 + c2];
            sp += a.x;
            sn += a.y;
        }
        P[(size_t)bi * BN + j0 + c2] = sp;
        N[(size_t)bi * BN + j0 + c2] = sn;
    }
}

// Fused tail: 128 blocks x 256. Each block owns 64 rows; the 4 waves split
// the 64 column-blocks (16 strided, coalesced 256B/wave), LDS combine,
// per-row loss (histogram read from precomputed global cnt), one
// atomicAdd of the pre-scaled block sum into out[0].
__global__ __launch_bounds__(256) void reduce_finalize_kernel(
        const int* __restrict__ labels, const float* __restrict__ P,
        const float* __restrict__ N, const int* __restrict__ cntG,
        float* __restrict__ out) {
    __shared__ float2 buf[4][64];
    int tid = threadIdx.x;
    int r = tid & 63, w = tid >> 6;
    int i = blockIdx.x * 64 + r;
    float p = 0.f, n = 0.f;
    #pragma unroll
    for (int u = 0; u < 16; ++u) {
        int c = w + u * 4;
        p += P[(size_t)c * BN + i];
        n += N[(size_t)c * BN + i];
    }
    buf[w][r] = (float2){p, n};
    __syncthreads();
    if (tid < 64) {
        float2 s0 = buf[0][r], s1 = buf[1][r], s2 = buf[2][r], s3 = buf[3][r];
        p = s0.x + s1.x + s2.x + s3.x;
        n = s0.y + s1.y + s2.y + s3.y;
        int   cl = cntG[labels[i]];
        float pm = p / fmaxf((float)(cl - 1), 1.0f);
        float nm = n / fmaxf((float)(BN - cl), 1.0f);
        float v  = ((cl - 1 > 0) && (BN - cl > 0))
                       ? -logf(pm / (pm + nm + EPSF)) : 0.0f;
        v *= (1.0f / (float)BN);
        #pragma unroll
        for (int m = 1; m < 64; m <<= 1) v += __shfl_xor(v, m, 64);
        if (r == 0) atomicAdd(out, v);
    }
}

extern "C" void kernel_launch(void* const* d_in, const int* in_sizes, int n_in,
                              void* d_out, int out_size, void* d_ws, size_t ws_size,
                              hipStream_t stream) {
    const float* emb   = (const float*)d_in[0];
    const int* labels  = (const int*)d_in[1];
    float* out         = (float*)d_out;

    // ws layout: E (8 MB reserved; fp8 uses 4, cnt lives at +4 MB) |
    // P (2 MB) | N (2 MB)
    unsigned char* E   = (unsigned char*)d_ws;
    int* cntG          = (int*)((char*)d_ws + (size_t)BN * DIM);
    float* P           = (float*)((char*)d_ws + (size_t)BN * DIM * 2);
    float* N           = P + (size_t)NB * BN;

    normalize_kernel<<<BN / 4, 256, 0, stream>>>(emb, E, cntG, out);
    gemm_epi_kernel<<<NTILES, 512, 0, stream>>>(E, labels, cntG, P, N);
    reduce_finalize_kernel<<<128, 256, 0, stream>>>(labels, P, N, cntG, out);
}